// Round 19
// baseline (403.393 us; speedup 1.0000x reference)
//
#include <hip/hip_runtime.h>
#include <hip/hip_bf16.h>

typedef unsigned short ushort_t;
typedef unsigned int uint_t;

#define S_LEN 4096
#define BATCH 4
#define DMODEL 1040
#define KPAD 1056          // 1040 padded to 33*32 (hs K)
#define KO 1152            // attn feature dim: 16 heads * 72; O-GEMM K
#define NPADW 1152
#define M_TOK 16384        // full M (4 batches x 4096)
#define KVSPLIT 16         // kv-state split count (16 x 64 bh = 1024 blocks)

using f32x4 = __attribute__((ext_vector_type(4))) float;
using bf16x8 = __attribute__((ext_vector_type(8))) __bf16;
using f16x8 = __attribute__((ext_vector_type(8))) _Float16;

// fp16 two-plane split, lo plane pre-scaled by 2^12
__device__ __forceinline__ void splitf16(float x, ushort_t& h, ushort_t& l) {
  _Float16 hf = (_Float16)x;
  float r = (x - (float)hf) * 4096.0f;
  _Float16 lf = (_Float16)r;
  h = __builtin_bit_cast(ushort_t, hf);
  l = __builtin_bit_cast(ushort_t, lf);
}

typedef const __attribute__((address_space(1))) unsigned int* gas_u32p;
typedef __attribute__((address_space(3))) unsigned int* las_u32p;
__device__ __forceinline__ void gload_lds16(const ushort_t* g, ushort_t* l) {
  __builtin_amdgcn_global_load_lds((gas_u32p)g, (las_u32p)l, 16, 0, 0);
}

// XCD-chunked tile map: XCD x owns m-panels [x*PPX, x*PPX+PPX), n-inner order.
__device__ __forceinline__ void tile_map(int lid, int NT, int PPX, int& mi_out, int& ni_out) {
  const int x = lid & 7, pos = lid >> 3;
  const int mi = pos / NT, ni = pos - mi * NT;
  mi_out = x * PPX + mi;
  ni_out = ni;
}

union pack8 { ushort_t u[8]; uint4 v; };

// ---------------- split hs rows [M_TOK][1040] f32 -> fp16 h/l' planes [M_TOK][KPAD] ---
__global__ __launch_bounds__(256) void split_hs_kernel(const float* __restrict__ hs,
                                                       ushort_t* __restrict__ hh,
                                                       ushort_t* __restrict__ hl) {
  const int C8 = KPAD / 8;  // 132
  int idx = blockIdx.x * 256 + threadIdx.x;
  if (idx >= M_TOK * C8) return;
  int row = idx / C8, col = (idx % C8) * 8;
  pack8 ph, pl;
  if (col < DMODEL) {
    const float* p = &hs[(size_t)row * DMODEL + col];
#pragma unroll
    for (int j = 0; j < 8; ++j) splitf16(p[j], ph.u[j], pl.u[j]);
  } else {
#pragma unroll
    for (int j = 0; j < 8; ++j) { ph.u[j] = 0; pl.u[j] = 0; }
  }
  size_t o = (size_t)row * KPAD + col;
  *reinterpret_cast<uint4*>(&hh[o]) = ph.v;
  *reinterpret_cast<uint4*>(&hl[o]) = pl.v;
}

// ------- Wq||Wk transpose+split (fp16 scaled): Wt[n<1024][k<1056] ---------------------
__global__ __launch_bounds__(256) void split_wqk_kernel(const float* __restrict__ Wq,
                                                        const float* __restrict__ Wk,
                                                        ushort_t* __restrict__ th,
                                                        ushort_t* __restrict__ tl) {
  const int C8 = KPAD / 8;
  int idx = blockIdx.x * 256 + threadIdx.x;
  if (idx >= 1024 * C8) return;
  int n = idx / C8, k = (idx % C8) * 8;
  pack8 ph, pl;
#pragma unroll
  for (int j = 0; j < 8; ++j) {
    int kk = k + j;
    float val = 0.f;
    if (kk < DMODEL) val = (n < 512) ? Wq[(size_t)kk * 512 + n] : Wk[(size_t)kk * 512 + (n - 512)];
    splitf16(val, ph.u[j], pl.u[j]);
  }
  size_t o = (size_t)n * KPAD + k;
  *reinterpret_cast<uint4*>(&th[o]) = ph.v;
  *reinterpret_cast<uint4*>(&tl[o]) = pl.v;
}

// ------- Wv transpose (fp16 hi), output column n' = h*72+e (v head stride 72) ---------
__global__ __launch_bounds__(256) void split_wv_kernel(const float* __restrict__ Wv,
                                                       ushort_t* __restrict__ th) {
  const int C8 = KPAD / 8;
  int idx = blockIdx.x * 256 + threadIdx.x;
  if (idx >= NPADW * C8) return;
  int n = idx / C8, k = (idx % C8) * 8;   // n = output column = h*72 + e
  int hh_ = n / 72, e = n % 72;
  pack8 ph;
#pragma unroll
  for (int j = 0; j < 8; ++j) {
    int kk = k + j;
    float val = (e < 65 && kk < DMODEL) ? Wv[(size_t)kk * DMODEL + (hh_ * 65 + e)] : 0.f;
    ph.u[j] = __builtin_bit_cast(ushort_t, (_Float16)val);
  }
  *reinterpret_cast<uint4*>(&th[(size_t)n * KPAD + k]) = ph.v;
}

// ------- Wo transpose (bf16 single plane) with attn k-mapping k' = h*72+e -------------
__global__ __launch_bounds__(256) void split_wo_kernel(const float* __restrict__ Wo,
                                                       ushort_t* __restrict__ th) {
  const int C8O = KO / 8;  // 144
  int idx = blockIdx.x * 256 + threadIdx.x;
  if (idx >= NPADW * C8O) return;
  int n = idx / C8O, k = (idx % C8O) * 8;
  pack8 ph;
#pragma unroll
  for (int j = 0; j < 8; ++j) {
    int kk = k + j;           // attn feature index = h*72 + e
    int h = kk / 72, e = kk % 72;
    float val = (n < DMODEL && e < 65) ? Wo[(size_t)(h * 65 + e) * DMODEL + n] : 0.f;
    ph.u[j] = __builtin_bit_cast(ushort_t, __float2bfloat16(val));
  }
  *reinterpret_cast<uint4*>(&th[(size_t)n * KO + k]) = ph.v;
}

// ------- QK GEMM: fp16 2-plane 3-product, 512 threads (8 waves), dbuf issue-early -----
__global__ __launch_bounds__(512, 4) void gemm_qk(const ushort_t* __restrict__ Ahg,
                                                  const ushort_t* __restrict__ Alg,
                                                  const ushort_t* __restrict__ Bhg,
                                                  const ushort_t* __restrict__ Blg,
                                                  float* __restrict__ C, int kdim) {
  __shared__ ushort_t Ah[2][4096], Al[2][4096], Bh[2][4096], Bl[2][4096];
  const int t = threadIdx.x;         // 0..511
  const int w = t >> 6, l = t & 63;  // 8 waves
  int mi, ni;
  tile_map(blockIdx.x, 8, 16, mi, ni);
  const int m0 = mi * 128, n0 = ni * 128;
  const int wm = w >> 2, wn = w & 3;  // 2 x 4
  const int row16 = l & 15, g = l >> 4;

  f32x4 acc[4][2], acc2[4][2];
#pragma unroll
  for (int m = 0; m < 4; ++m)
#pragma unroll
    for (int n = 0; n < 2; ++n) { acc[m][n] = (f32x4){0,0,0,0}; acc2[m][n] = (f32x4){0,0,0,0}; }

  const int chunk = t;               // one 8-u16 chunk per plane per thread
  const int r0 = chunk >> 2;         // 0..127
  const int ch0 = (chunk & 3) ^ ((r0 ^ (r0 >> 2)) & 3);

#define STAGE_QK(K0, BUF)                                                       \
  {                                                                             \
    const size_t ga = (size_t)(m0 + r0) * kdim + (K0) + ch0 * 8;                \
    const size_t gb = (size_t)(n0 + r0) * kdim + (K0) + ch0 * 8;                \
    gload_lds16(Ahg + ga, &Ah[BUF][chunk * 8]);                                 \
    gload_lds16(Alg + ga, &Al[BUF][chunk * 8]);                                 \
    gload_lds16(Bhg + gb, &Bh[BUF][chunk * 8]);                                 \
    gload_lds16(Blg + gb, &Bl[BUF][chunk * 8]);                                 \
  }

  STAGE_QK(0, 0);
  __syncthreads();
  for (int k0 = 0, it = 0; k0 < kdim; k0 += 32, ++it) {
    const int cur = it & 1;
    if (k0 + 32 < kdim) STAGE_QK(k0 + 32, cur ^ 1);
    f16x8 fah[4], fal[4], fbh[2], fbl[2];
#pragma unroll
    for (int f = 0; f < 4; ++f) {
      const int ra = wm * 64 + f * 16 + row16;
      const int ca = (g ^ ((ra ^ (ra >> 2)) & 3)) << 3;
      fah[f] = *(const f16x8*)&Ah[cur][ra * 32 + ca];
      fal[f] = *(const f16x8*)&Al[cur][ra * 32 + ca];
    }
#pragma unroll
    for (int f = 0; f < 2; ++f) {
      const int rb = wn * 32 + f * 16 + row16;
      const int cb = (g ^ ((rb ^ (rb >> 2)) & 3)) << 3;
      fbh[f] = *(const f16x8*)&Bh[cur][rb * 32 + cb];
      fbl[f] = *(const f16x8*)&Bl[cur][rb * 32 + cb];
    }
#pragma unroll
    for (int m = 0; m < 4; ++m)
#pragma unroll
      for (int n = 0; n < 2; ++n) {
        acc[m][n]  = __builtin_amdgcn_mfma_f32_16x16x32_f16(fah[m], fbh[n], acc[m][n], 0, 0, 0);
        acc2[m][n] = __builtin_amdgcn_mfma_f32_16x16x32_f16(fah[m], fbl[n], acc2[m][n], 0, 0, 0);
        acc2[m][n] = __builtin_amdgcn_mfma_f32_16x16x32_f16(fal[m], fbh[n], acc2[m][n], 0, 0, 0);
      }
    __syncthreads();
  }
#undef STAGE_QK

  const float S2 = 1.0f / 4096.0f;
#pragma unroll
  for (int m = 0; m < 4; ++m)
#pragma unroll
    for (int n = 0; n < 2; ++n) {
      const int col = n0 + wn * 32 + n * 16 + row16;
      const int rowb = m0 + wm * 64 + m * 16 + g * 4;
#pragma unroll
      for (int i = 0; i < 4; ++i)
        C[(size_t)(rowb + i) * 1024 + col] = acc[m][n][i] + acc2[m][n][i] * S2;
    }
}

// ------- V GEMM: 256x128 tile, fp16 hi 1-product, 512 threads, fp16 output ------------
__global__ __launch_bounds__(512, 4) void gemm_v(const ushort_t* __restrict__ Ahg,
                                                 const ushort_t* __restrict__ Bhg,
                                                 ushort_t* __restrict__ Cv, int kdim) {
  __shared__ ushort_t Ah[2][8192], Bh[2][4096];
  const int t = threadIdx.x;
  const int w = t >> 6, l = t & 63;
  int mi, ni;
  tile_map(blockIdx.x, 9, 8, mi, ni);
  const int m0 = mi * 256, n0 = ni * 128;
  const int wm = w >> 1, wn = w & 1;   // 4 x 2 -> per-wave 64x64
  const int row16 = l & 15, g = l >> 4;

  f32x4 acc[4][4];
#pragma unroll
  for (int m = 0; m < 4; ++m)
#pragma unroll
    for (int n = 0; n < 4; ++n) acc[m][n] = (f32x4){0,0,0,0};

  const int ra0 = t >> 2, ra1 = (t + 512) >> 2;
  const int ca0 = (t & 3) ^ ((ra0 ^ (ra0 >> 2)) & 3);
  const int ca1 = (t & 3) ^ ((ra1 ^ (ra1 >> 2)) & 3);

#define STAGE_V(K0, BUF)                                                        \
  {                                                                             \
    gload_lds16(Ahg + (size_t)(m0 + ra0) * kdim + (K0) + ca0 * 8,               \
                &Ah[BUF][t * 8]);                                               \
    gload_lds16(Ahg + (size_t)(m0 + ra1) * kdim + (K0) + ca1 * 8,               \
                &Ah[BUF][(t + 512) * 8]);                                       \
    gload_lds16(Bhg + (size_t)(n0 + ra0) * kdim + (K0) + ca0 * 8,               \
                &Bh[BUF][t * 8]);                                               \
  }

  STAGE_V(0, 0);
  __syncthreads();
  for (int k0 = 0, it = 0; k0 < kdim; k0 += 32, ++it) {
    const int cur = it & 1;
    if (k0 + 32 < kdim) STAGE_V(k0 + 32, cur ^ 1);
    f16x8 fah[4], fbh[4];
#pragma unroll
    for (int f = 0; f < 4; ++f) {
      const int ra = wm * 64 + f * 16 + row16;
      const int ca = (g ^ ((ra ^ (ra >> 2)) & 3)) << 3;
      fah[f] = *(const f16x8*)&Ah[cur][ra * 32 + ca];
      const int rb = wn * 64 + f * 16 + row16;
      const int cb = (g ^ ((rb ^ (rb >> 2)) & 3)) << 3;
      fbh[f] = *(const f16x8*)&Bh[cur][rb * 32 + cb];
    }
#pragma unroll
    for (int m = 0; m < 4; ++m)
#pragma unroll
      for (int n = 0; n < 4; ++n)
        acc[m][n] = __builtin_amdgcn_mfma_f32_16x16x32_f16(fah[m], fbh[n], acc[m][n], 0, 0, 0);
    __syncthreads();
  }
#undef STAGE_V

#pragma unroll
  for (int m = 0; m < 4; ++m)
#pragma unroll
    for (int n = 0; n < 4; ++n) {
      const int col = n0 + wn * 64 + n * 16 + row16;
      const int rowb = m0 + wm * 64 + m * 16 + g * 4;
#pragma unroll
      for (int i = 0; i < 4; ++i)
        Cv[(size_t)(rowb + i) * 1152 + col] =
            __builtin_bit_cast(ushort_t, (_Float16)acc[m][n][i]);
    }
}

// ------- O GEMM: 256x128 tile, single-plane bf16, 512 threads -------------------------
__global__ __launch_bounds__(512, 4) void gemm_o(const ushort_t* __restrict__ Ahg,
                                                 const ushort_t* __restrict__ Bhg,
                                                 float* __restrict__ C, int kdim) {
  __shared__ ushort_t Ah[2][8192], Bh[2][4096];
  const int t = threadIdx.x;
  const int w = t >> 6, l = t & 63;
  int mi, ni;
  tile_map(blockIdx.x, 9, 8, mi, ni);
  const int m0 = mi * 256, n0 = ni * 128;
  const int wm = w >> 1, wn = w & 1;
  const int row16 = l & 15, g = l >> 4;

  f32x4 acc[4][4];
#pragma unroll
  for (int m = 0; m < 4; ++m)
#pragma unroll
    for (int n = 0; n < 4; ++n) acc[m][n] = (f32x4){0,0,0,0};

  const int ra0 = t >> 2, ra1 = (t + 512) >> 2;
  const int ca0 = (t & 3) ^ ((ra0 ^ (ra0 >> 2)) & 3);
  const int ca1 = (t & 3) ^ ((ra1 ^ (ra1 >> 2)) & 3);

#define STAGE_O(K0, BUF)                                                        \
  {                                                                             \
    gload_lds16(Ahg + (size_t)(m0 + ra0) * kdim + (K0) + ca0 * 8,               \
                &Ah[BUF][t * 8]);                                               \
    gload_lds16(Ahg + (size_t)(m0 + ra1) * kdim + (K0) + ca1 * 8,               \
                &Ah[BUF][(t + 512) * 8]);                                       \
    gload_lds16(Bhg + (size_t)(n0 + ra0) * kdim + (K0) + ca0 * 8,               \
                &Bh[BUF][t * 8]);                                               \
  }

  STAGE_O(0, 0);
  __syncthreads();
  for (int k0 = 0, it = 0; k0 < kdim; k0 += 32, ++it) {
    const int cur = it & 1;
    if (k0 + 32 < kdim) STAGE_O(k0 + 32, cur ^ 1);
    bf16x8 fah[4], fbh[4];
#pragma unroll
    for (int f = 0; f < 4; ++f) {
      const int ra = wm * 64 + f * 16 + row16;
      const int ca = (g ^ ((ra ^ (ra >> 2)) & 3)) << 3;
      fah[f] = *(const bf16x8*)&Ah[cur][ra * 32 + ca];
      const int rb = wn * 64 + f * 16 + row16;
      const int cb = (g ^ ((rb ^ (rb >> 2)) & 3)) << 3;
      fbh[f] = *(const bf16x8*)&Bh[cur][rb * 32 + cb];
    }
#pragma unroll
    for (int m = 0; m < 4; ++m)
#pragma unroll
      for (int n = 0; n < 4; ++n)
        acc[m][n] = __builtin_amdgcn_mfma_f32_16x16x32_bf16(fah[m], fbh[n], acc[m][n], 0, 0, 0);
    __syncthreads();
  }
#undef STAGE_O

#pragma unroll
  for (int m = 0; m < 4; ++m)
#pragma unroll
    for (int n = 0; n < 4; ++n) {
      const int col = n0 + wn * 64 + n * 16 + row16;
      if (col < DMODEL) {
        const int rowb = m0 + wm * 64 + m * 16 + g * 4;
#pragma unroll
        for (int i = 0; i < 4; ++i) C[(size_t)(rowb + i) * DMODEL + col] = acc[m][n][i];
      }
    }
}

// ---------------- kv state partials: phi(k)^T @ v per (bh, split) ---------------------
// Vectorized fill (stride-72 v layout for aligned uint4 loads); balanced 13x17 tiles.
// NO min-wave clamp (round-11 lesson: (256,8) forced VGPR=32 -> acc spill -> 1.6 GB).
__global__ __launch_bounds__(256) void kv_kernel(const float* __restrict__ qk,
                                                 const ushort_t* __restrict__ vbuf,
                                                 float* __restrict__ kvpart,
                                                 float* __restrict__ kspart) {
  const int bh = blockIdx.x;    // 0..63
  const int split = blockIdx.y; // 0..KVSPLIT-1
  const int b = bh >> 4, h = bh & 15;
  __shared__ float ks[64][68];
  __shared__ float vs[64][68];
  const int tid = threadIdx.x;
  const int fr = tid >> 2;        // fill row 0..63
  const int fp = tid & 3;         // fill part 0..3
  const int d0 = (tid / 17) * 5;  // 0,5,...,60
  const int e0 = (tid % 17) * 4;  // 0,4,...,64
  const bool active = (tid < 221);
  float acc[5][4] = {};
  float kcol = 0.f;

  for (int chunk = 0; chunk < 4; ++chunk) {
    const int nb = split * 256 + chunk * 64;
    {
      const size_t row = (size_t)(b * S_LEN + nb + fr);
      const float* kx = &qk[row * 1024 + 512 + h * 32 + fp * 8];
      float4 x0 = *reinterpret_cast<const float4*>(kx);
      float4 x1 = *reinterpret_cast<const float4*>(kx + 4);
      float xs[8] = {x0.x, x0.y, x0.z, x0.w, x1.x, x1.y, x1.z, x1.w};
#pragma unroll
      for (int j = 0; j < 8; ++j) {
        ks[fr][1 + fp * 8 + j] = xs[j];
        ks[fr][33 + fp * 8 + j] = 0.5f * xs[j] * xs[j];
      }
      if (fp == 0) ks[fr][0] = 1.f;
      const ushort_t* vp = &vbuf[row * 1152 + h * 72 + fp * 16];
      uint4 v0 = *reinterpret_cast<const uint4*>(vp);
      uint4 v1 = *reinterpret_cast<const uint4*>(vp + 8);
      const ushort_t* vu0 = reinterpret_cast<const ushort_t*>(&v0);
      const ushort_t* vu1 = reinterpret_cast<const ushort_t*>(&v1);
#pragma unroll
      for (int j = 0; j < 8; ++j) {
        vs[fr][fp * 16 + j] = (float)__builtin_bit_cast(_Float16, vu0[j]);
        vs[fr][fp * 16 + 8 + j] = (float)__builtin_bit_cast(_Float16, vu1[j]);
      }
      if (fp == 3) vs[fr][64] = (float)__builtin_bit_cast(_Float16, vbuf[row * 1152 + h * 72 + 64]);
    }
    __syncthreads();
    if (active) {
      for (int r = 0; r < 64; ++r) {
        float a[5], v[4];
#pragma unroll
        for (int i = 0; i < 5; ++i) a[i] = ks[r][d0 + i];
#pragma unroll
        for (int j = 0; j < 4; ++j) v[j] = vs[r][e0 + j];
#pragma unroll
        for (int i = 0; i < 5; ++i)
#pragma unroll
          for (int j = 0; j < 4; ++j) acc[i][j] += a[i] * v[j];
      }
    }
    if (tid < 65) {
      float s = 0.f;
      for (int r = 0; r < 64; ++r) s += ks[r][tid];
      kcol += s;
    }
    __syncthreads();
  }

  if (active) {
    float* kvp = kvpart + ((size_t)split * 64 + bh) * 4225;
#pragma unroll
    for (int i = 0; i < 5; ++i)
#pragma unroll
      for (int j = 0; j < 4; ++j) {
        int e = e0 + j;
        if (e < 65) kvp[(d0 + i) * 65 + e] = acc[i][j];
      }
  }
  if (tid < 65) kspart[((size_t)split * 64 + bh) * 65 + tid] = kcol;
}

__global__ __launch_bounds__(256) void kv_reduce(const float* __restrict__ kvpart,
                                                 const float* __restrict__ kspart,
                                                 float* __restrict__ kv,
                                                 float* __restrict__ ksum) {
  const int NKV = 64 * 4225;
  const int NKS = 64 * 65;
  int i = blockIdx.x * 256 + threadIdx.x;
  if (i < NKV) {
    float s = 0.f;
#pragma unroll 8
    for (int p = 0; p < KVSPLIT; ++p) s += kvpart[(size_t)p * NKV + i];
    kv[i] = s;
  } else if (i < NKV + NKS) {
    int j = i - NKV;
    float s = 0.f;
#pragma unroll 8
    for (int p = 0; p < KVSPLIT; ++p) s += kspart[p * NKS + j];
    ksum[j] = s;
  }
}

// ------- phi(q)@kv, normalize, mask; write attn bf16 (single plane), k' = h*72+e ------
// TRANSPOSED phi store phis_t[d][token] (row stride 128 floats = 512B, 16B-aligned):
// per d, one float4 covers this thread's 4 consecutive tokens -> main-loop LDS =
// 3x b128 (was 2x b128 + 4 scalar). Fill writes are 8-way-conflicted but one-time.
__global__ __launch_bounds__(256) void qkv_kernel(const float* __restrict__ qk,
                                                  const float* __restrict__ kv,
                                                  const float* __restrict__ ksum,
                                                  const int* __restrict__ mask,
                                                  uint_t* __restrict__ ath32) {
  const int gx = blockIdx.x;   // 0..31 (128-token chunks within batch)
  const int bh = blockIdx.y;   // 0..63
  const int b = bh >> 4, h = bh & 15;
  __shared__ float kvs[65 * 68];      // 17.7 KB
  __shared__ float phis_t[68][128];   // 34.8 KB  [d][token]
  __shared__ float kss[65];
  __shared__ float qsums[128];
  const int tid = threadIdx.x;

  const float* kvp = kv + (size_t)bh * 4225;
  for (int i = tid; i < 4225; i += 256) kvs[(i / 65) * 68 + (i % 65)] = kvp[i];
  // fill phi transposed: thread (tok, fq) reads float4 of q, writes 8 scalars
  for (int idx = tid; idx < 128 * 8; idx += 256) {
    int tok = idx >> 3, fq = idx & 7;
    size_t row = (size_t)(b * S_LEN + gx * 128 + tok);
    float4 v = *reinterpret_cast<const float4*>(&qk[row * 1024 + h * 32 + fq * 4]);
    float xs[4] = {v.x, v.y, v.z, v.w};
#pragma unroll
    for (int j = 0; j < 4; ++j) {
      phis_t[1 + fq * 4 + j][tok] = xs[j];
      phis_t[33 + fq * 4 + j][tok] = 0.5f * xs[j] * xs[j];
    }
  }
  if (tid < 128) phis_t[0][tid] = 1.f;
  if (tid < 65) kss[tid] = ksum[bh * 65 + tid];
  __syncthreads();
  if (tid < 128) {
    float s = 0.f;
    for (int d = 0; d < 65; ++d) s += phis_t[d][tid];
    qsums[tid] = s;
  }
  __syncthreads();

  const int tt = tid >> 3, fg = tid & 7;  // thread owns tokens 4*tt .. 4*tt+3
  float accs[4][8];
#pragma unroll
  for (int c = 0; c < 4; ++c)
#pragma unroll
    for (int j = 0; j < 8; ++j) accs[c][j] = 0.f;
  float a64[4] = {0.f, 0.f, 0.f, 0.f};

#pragma unroll 4
  for (int d = 0; d < 65; ++d) {
    const float* kr = &kvs[d * 68 + fg * 8];
    float4 va = *reinterpret_cast<const float4*>(kr);
    float4 vb = *reinterpret_cast<const float4*>(kr + 4);
    float kv64 = kvs[d * 68 + 64];
    float4 pv = *reinterpret_cast<const float4*>(&phis_t[d][tt * 4]);
    float ps[4] = {pv.x, pv.y, pv.z, pv.w};
#pragma unroll
    for (int c = 0; c < 4; ++c) {
      float p = ps[c];
      accs[c][0] += p * va.x; accs[c][1] += p * va.y;
      accs[c][2] += p * va.z; accs[c][3] += p * va.w;
      accs[c][4] += p * vb.x; accs[c][5] += p * vb.y;
      accs[c][6] += p * vb.z; accs[c][7] += p * vb.w;
      if (fg == 0) a64[c] += p * kv64;
    }
  }

#pragma unroll
  for (int c = 0; c < 4; ++c) {
    const int tok = tt * 4 + c;
    const int s_in_b = gx * 128 + tok;
    const size_t row = (size_t)(b * S_LEN + s_in_b);
    const int m = mask[b * S_LEN + s_in_b];
    const float qs = qsums[tok];
    const float fm = (m == 0) ? 0.f : 1.f;
    float o[8];
#pragma unroll
    for (int j = 0; j < 8; ++j) {
      float z = qs * kss[fg * 8 + j] + 1e-9f;
      o[j] = fm * accs[c][j] / z;
    }
    const size_t base = row * 576 + h * 36 + fg * 4;  // u32 units; row = 1152 u16
    pack8 phh;
#pragma unroll
    for (int j = 0; j < 8; ++j)
      phh.u[j] = __builtin_bit_cast(ushort_t, __float2bfloat16(o[j]));
    *reinterpret_cast<uint4*>(&ath32[base]) = phh.v;
    if (fg == 0) {
      float z = qs * kss[64] + 1e-9f;
      float o64 = fm * a64[c] / z;
      uint4 tailh = {(uint_t)__builtin_bit_cast(ushort_t, __float2bfloat16(o64)), 0u, 0u, 0u};
      *reinterpret_cast<uint4*>(&ath32[row * 576 + h * 36 + 32]) = tailh;
    }
  }
}

extern "C" void kernel_launch(void* const* d_in, const int* in_sizes, int n_in,
                              void* d_out, int out_size, void* d_ws, size_t ws_size,
                              hipStream_t stream) {
  const float* hs = (const float*)d_in[0];
  const int* mask = (const int*)d_in[1];
  const float* Wq = (const float*)d_in[2];
  const float* Wk = (const float*)d_in[3];
  const float* Wv = (const float*)d_in[4];
  const float* Wo = (const float*)d_in[5];
  float* out = (float*)d_out;

  // Liveness-aliased full-M layout (148.9 MB total):
  //   R_A (34.6 MB): hsh (split_hs..gemm_v) -> kv+ksum+kvpart+kspart (kv_kernel..qkv)
  //   R_B (37.75 MB): hsl (..gemm_qk) -> vbuf (gemm_v..kv_kernel) -> attn (qkv..gemm_o)
  //   R_C (67.1 MB): qkbuf (gemm_qk..qkv)
  //   R_W (9.4 MB): weight planes
  const size_t RA_BYTES = (size_t)M_TOK * KPAD * 2;        // 34.6 MB
  const size_t RB_BYTES = (size_t)M_TOK * 1152 * 2;        // 37.75 MB

  char* base = (char*)d_ws;
  ushort_t* hsh = (ushort_t*)base;                         // R_A as hsh
  float* kv = (float*)base;                                // R_A as kv state
  float* ksum = kv + 64 * 4225;
  float* kvpart = ksum + 64 * 65;
  float* kspart = kvpart + (size_t)KVSPLIT * 64 * 4225;
  char* rb = base + RA_BYTES;
  ushort_t* hsl = (ushort_t*)rb;                           // R_B as hsl
  ushort_t* vbuf = (ushort_t*)rb;                          // R_B as v (fp16, stride-72)
  uint_t* ath32 = (uint_t*)rb;                             // R_B as attn (bf16)
  char* rc = rb + RB_BYTES;
  float* qkbuf = (float*)rc;                               // R_C
  char* rw = rc + (size_t)M_TOK * 1024 * 4;
  ushort_t* Wqkh = (ushort_t*)rw;                          // [1024][1056] fp16 hi
  ushort_t* Wqkl = Wqkh + (size_t)1024 * KPAD;             // lo
  ushort_t* Wvh = Wqkl + (size_t)1024 * KPAD;              // [1152][1056] fp16 hi
  ushort_t* Woh = Wvh + (size_t)NPADW * KPAD;              // [1152][1152] bf16

  dim3 blk(256);
  const int C8 = KPAD / 8;
  const int C8O = KO / 8;

  split_wqk_kernel<<<(1024 * C8 + 255) / 256, blk, 0, stream>>>(Wq, Wk, Wqkh, Wqkl);
  split_wv_kernel<<<(NPADW * C8 + 255) / 256, blk, 0, stream>>>(Wv, Wvh);
  split_wo_kernel<<<(NPADW * C8O + 255) / 256, blk, 0, stream>>>(Wo, Woh);

  split_hs_kernel<<<(M_TOK * C8 + 255) / 256, blk, 0, stream>>>(hs, hsh, hsl);

  // q|k projection: fp32-grade 3-product fp16; 1024 blocks x 512 threads
  gemm_qk<<<1024, dim3(512), 0, stream>>>(hsh, hsl, Wqkh, Wqkl, qkbuf, KPAD);
  // v projection: 256x128 tile, 1-product fp16, stride-72 head layout
  gemm_v<<<576, dim3(512), 0, stream>>>(hsh, Wvh, vbuf, KPAD);

  // kv state (writes into R_A — hsh dead after gemm_v)
  kv_kernel<<<dim3(64, KVSPLIT), blk, 0, stream>>>(qkbuf, vbuf, kvpart, kspart);
  kv_reduce<<<(64 * 4225 + 64 * 65 + 255) / 256, blk, 0, stream>>>(kvpart, kspart, kv, ksum);

  // attn (overwrites vbuf — dead after kv_kernel)
  qkv_kernel<<<dim3(32, 64), blk, 0, stream>>>(qkbuf, kv, ksum, mask, ath32);

  // output projection: 256x128 tile, single-plane bf16
  gemm_o<<<576, dim3(512), 0, stream>>>((ushort_t*)ath32, Woh, out, KO);
}

// Round 20
// 390.156 us; speedup vs baseline: 1.0339x; 1.0339x over previous
//
#include <hip/hip_runtime.h>
#include <hip/hip_bf16.h>

typedef unsigned short ushort_t;
typedef unsigned int uint_t;

#define S_LEN 4096
#define BATCH 4
#define DMODEL 1040
#define KPAD 1056          // 1040 padded to 33*32 (hs K)
#define KO 1152            // attn feature dim: 16 heads * 72; O-GEMM K
#define NPADW 1152
#define M_TOK 16384        // full M (4 batches x 4096)
#define KVSPLIT 16         // kv-state split count (16 x 64 bh = 1024 blocks)

// fused-split block ranges (exact multiples of 256)
#define HS_BLK 8448        // M_TOK*132/256
#define WQK_BLK 528        // 1024*132/256
#define WV_BLK 594         // 1152*132/256
#define WO_BLK 648         // 1152*144/256

using f32x4 = __attribute__((ext_vector_type(4))) float;
using bf16x8 = __attribute__((ext_vector_type(8))) __bf16;
using f16x8 = __attribute__((ext_vector_type(8))) _Float16;

// fp16 two-plane split, lo plane pre-scaled by 2^12
__device__ __forceinline__ void splitf16(float x, ushort_t& h, ushort_t& l) {
  _Float16 hf = (_Float16)x;
  float r = (x - (float)hf) * 4096.0f;
  _Float16 lf = (_Float16)r;
  h = __builtin_bit_cast(ushort_t, hf);
  l = __builtin_bit_cast(ushort_t, lf);
}

typedef const __attribute__((address_space(1))) unsigned int* gas_u32p;
typedef __attribute__((address_space(3))) unsigned int* las_u32p;
__device__ __forceinline__ void gload_lds16(const ushort_t* g, ushort_t* l) {
  __builtin_amdgcn_global_load_lds((gas_u32p)g, (las_u32p)l, 16, 0, 0);
}

// XCD-chunked tile map: XCD x owns m-panels [x*PPX, x*PPX+PPX), n-inner order.
__device__ __forceinline__ void tile_map(int lid, int NT, int PPX, int& mi_out, int& ni_out) {
  const int x = lid & 7, pos = lid >> 3;
  const int mi = pos / NT, ni = pos - mi * NT;
  mi_out = x * PPX + mi;
  ni_out = ni;
}

union pack8 { ushort_t u[8]; uint4 v; };

// ------- fused preprocessing: hs split | Wq||Wk split | Wv transpose | Wo transpose ---
// One dispatch replaces 4 (saves launch gaps; small weight-splits co-schedule with hs).
__global__ __launch_bounds__(256) void split_all(const float* __restrict__ hs,
                                                 const float* __restrict__ Wq,
                                                 const float* __restrict__ Wk,
                                                 const float* __restrict__ Wv,
                                                 const float* __restrict__ Wo,
                                                 ushort_t* __restrict__ hh,
                                                 ushort_t* __restrict__ hl,
                                                 ushort_t* __restrict__ Wqkh,
                                                 ushort_t* __restrict__ Wqkl,
                                                 ushort_t* __restrict__ Wvh,
                                                 ushort_t* __restrict__ Woh) {
  const int bid = blockIdx.x;
  const int C8 = KPAD / 8;   // 132
  const int C8O = KO / 8;    // 144

  if (bid < HS_BLK) {
    // ---- hs rows [M_TOK][1040] f32 -> fp16 h/l' planes [M_TOK][KPAD] ----
    int idx = bid * 256 + threadIdx.x;
    int row = idx / C8, col = (idx % C8) * 8;
    pack8 ph, pl;
    if (col < DMODEL) {
      const float* p = &hs[(size_t)row * DMODEL + col];
#pragma unroll
      for (int j = 0; j < 8; ++j) splitf16(p[j], ph.u[j], pl.u[j]);
    } else {
#pragma unroll
      for (int j = 0; j < 8; ++j) { ph.u[j] = 0; pl.u[j] = 0; }
    }
    size_t o = (size_t)row * KPAD + col;
    *reinterpret_cast<uint4*>(&hh[o]) = ph.v;
    *reinterpret_cast<uint4*>(&hl[o]) = pl.v;
  } else if (bid < HS_BLK + WQK_BLK) {
    // ---- Wq||Wk transpose+split (fp16 scaled): Wt[n<1024][k<1056] ----
    int idx = (bid - HS_BLK) * 256 + threadIdx.x;
    int n = idx / C8, k = (idx % C8) * 8;
    pack8 ph, pl;
#pragma unroll
    for (int j = 0; j < 8; ++j) {
      int kk = k + j;
      float val = 0.f;
      if (kk < DMODEL) val = (n < 512) ? Wq[(size_t)kk * 512 + n] : Wk[(size_t)kk * 512 + (n - 512)];
      splitf16(val, ph.u[j], pl.u[j]);
    }
    size_t o = (size_t)n * KPAD + k;
    *reinterpret_cast<uint4*>(&Wqkh[o]) = ph.v;
    *reinterpret_cast<uint4*>(&Wqkl[o]) = pl.v;
  } else if (bid < HS_BLK + WQK_BLK + WV_BLK) {
    // ---- Wv transpose (fp16 hi), output column n' = h*72+e (v head stride 72) ----
    int idx = (bid - HS_BLK - WQK_BLK) * 256 + threadIdx.x;
    int n = idx / C8, k = (idx % C8) * 8;   // n = output column = h*72 + e
    int hh_ = n / 72, e = n % 72;
    pack8 ph;
#pragma unroll
    for (int j = 0; j < 8; ++j) {
      int kk = k + j;
      float val = (e < 65 && kk < DMODEL) ? Wv[(size_t)kk * DMODEL + (hh_ * 65 + e)] : 0.f;
      ph.u[j] = __builtin_bit_cast(ushort_t, (_Float16)val);
    }
    *reinterpret_cast<uint4*>(&Wvh[(size_t)n * KPAD + k]) = ph.v;
  } else {
    // ---- Wo transpose (bf16 single plane) with attn k-mapping k' = h*72+e ----
    int idx = (bid - HS_BLK - WQK_BLK - WV_BLK) * 256 + threadIdx.x;
    int n = idx / C8O, k = (idx % C8O) * 8;
    pack8 ph;
#pragma unroll
    for (int j = 0; j < 8; ++j) {
      int kk = k + j;           // attn feature index = h*72 + e
      int h = kk / 72, e = kk % 72;
      float val = (n < DMODEL && e < 65) ? Wo[(size_t)(h * 65 + e) * DMODEL + n] : 0.f;
      ph.u[j] = __builtin_bit_cast(ushort_t, __float2bfloat16(val));
    }
    *reinterpret_cast<uint4*>(&Woh[(size_t)n * KO + k]) = ph.v;
  }
}

// ------- QK GEMM: fp16 2-plane 3-product, 512 threads (8 waves), dbuf issue-early -----
__global__ __launch_bounds__(512, 4) void gemm_qk(const ushort_t* __restrict__ Ahg,
                                                  const ushort_t* __restrict__ Alg,
                                                  const ushort_t* __restrict__ Bhg,
                                                  const ushort_t* __restrict__ Blg,
                                                  float* __restrict__ C, int kdim) {
  __shared__ ushort_t Ah[2][4096], Al[2][4096], Bh[2][4096], Bl[2][4096];
  const int t = threadIdx.x;         // 0..511
  const int w = t >> 6, l = t & 63;  // 8 waves
  int mi, ni;
  tile_map(blockIdx.x, 8, 16, mi, ni);
  const int m0 = mi * 128, n0 = ni * 128;
  const int wm = w >> 2, wn = w & 3;  // 2 x 4
  const int row16 = l & 15, g = l >> 4;

  f32x4 acc[4][2], acc2[4][2];
#pragma unroll
  for (int m = 0; m < 4; ++m)
#pragma unroll
    for (int n = 0; n < 2; ++n) { acc[m][n] = (f32x4){0,0,0,0}; acc2[m][n] = (f32x4){0,0,0,0}; }

  const int chunk = t;               // one 8-u16 chunk per plane per thread
  const int r0 = chunk >> 2;         // 0..127
  const int ch0 = (chunk & 3) ^ ((r0 ^ (r0 >> 2)) & 3);

#define STAGE_QK(K0, BUF)                                                       \
  {                                                                             \
    const size_t ga = (size_t)(m0 + r0) * kdim + (K0) + ch0 * 8;                \
    const size_t gb = (size_t)(n0 + r0) * kdim + (K0) + ch0 * 8;                \
    gload_lds16(Ahg + ga, &Ah[BUF][chunk * 8]);                                 \
    gload_lds16(Alg + ga, &Al[BUF][chunk * 8]);                                 \
    gload_lds16(Bhg + gb, &Bh[BUF][chunk * 8]);                                 \
    gload_lds16(Blg + gb, &Bl[BUF][chunk * 8]);                                 \
  }

  STAGE_QK(0, 0);
  __syncthreads();
  for (int k0 = 0, it = 0; k0 < kdim; k0 += 32, ++it) {
    const int cur = it & 1;
    if (k0 + 32 < kdim) STAGE_QK(k0 + 32, cur ^ 1);
    f16x8 fah[4], fal[4], fbh[2], fbl[2];
#pragma unroll
    for (int f = 0; f < 4; ++f) {
      const int ra = wm * 64 + f * 16 + row16;
      const int ca = (g ^ ((ra ^ (ra >> 2)) & 3)) << 3;
      fah[f] = *(const f16x8*)&Ah[cur][ra * 32 + ca];
      fal[f] = *(const f16x8*)&Al[cur][ra * 32 + ca];
    }
#pragma unroll
    for (int f = 0; f < 2; ++f) {
      const int rb = wn * 32 + f * 16 + row16;
      const int cb = (g ^ ((rb ^ (rb >> 2)) & 3)) << 3;
      fbh[f] = *(const f16x8*)&Bh[cur][rb * 32 + cb];
      fbl[f] = *(const f16x8*)&Bl[cur][rb * 32 + cb];
    }
#pragma unroll
    for (int m = 0; m < 4; ++m)
#pragma unroll
      for (int n = 0; n < 2; ++n) {
        acc[m][n]  = __builtin_amdgcn_mfma_f32_16x16x32_f16(fah[m], fbh[n], acc[m][n], 0, 0, 0);
        acc2[m][n] = __builtin_amdgcn_mfma_f32_16x16x32_f16(fah[m], fbl[n], acc2[m][n], 0, 0, 0);
        acc2[m][n] = __builtin_amdgcn_mfma_f32_16x16x32_f16(fal[m], fbh[n], acc2[m][n], 0, 0, 0);
      }
    __syncthreads();
  }
#undef STAGE_QK

  const float S2 = 1.0f / 4096.0f;
#pragma unroll
  for (int m = 0; m < 4; ++m)
#pragma unroll
    for (int n = 0; n < 2; ++n) {
      const int col = n0 + wn * 32 + n * 16 + row16;
      const int rowb = m0 + wm * 64 + m * 16 + g * 4;
#pragma unroll
      for (int i = 0; i < 4; ++i)
        C[(size_t)(rowb + i) * 1024 + col] = acc[m][n][i] + acc2[m][n][i] * S2;
    }
}

// ------- V GEMM: 256x128 tile, fp16 hi 1-product, 512 threads, fp16 output ------------
__global__ __launch_bounds__(512, 4) void gemm_v(const ushort_t* __restrict__ Ahg,
                                                 const ushort_t* __restrict__ Bhg,
                                                 ushort_t* __restrict__ Cv, int kdim) {
  __shared__ ushort_t Ah[2][8192], Bh[2][4096];
  const int t = threadIdx.x;
  const int w = t >> 6, l = t & 63;
  int mi, ni;
  tile_map(blockIdx.x, 9, 8, mi, ni);
  const int m0 = mi * 256, n0 = ni * 128;
  const int wm = w >> 1, wn = w & 1;   // 4 x 2 -> per-wave 64x64
  const int row16 = l & 15, g = l >> 4;

  f32x4 acc[4][4];
#pragma unroll
  for (int m = 0; m < 4; ++m)
#pragma unroll
    for (int n = 0; n < 4; ++n) acc[m][n] = (f32x4){0,0,0,0};

  const int ra0 = t >> 2, ra1 = (t + 512) >> 2;
  const int ca0 = (t & 3) ^ ((ra0 ^ (ra0 >> 2)) & 3);
  const int ca1 = (t & 3) ^ ((ra1 ^ (ra1 >> 2)) & 3);

#define STAGE_V(K0, BUF)                                                        \
  {                                                                             \
    gload_lds16(Ahg + (size_t)(m0 + ra0) * kdim + (K0) + ca0 * 8,               \
                &Ah[BUF][t * 8]);                                               \
    gload_lds16(Ahg + (size_t)(m0 + ra1) * kdim + (K0) + ca1 * 8,               \
                &Ah[BUF][(t + 512) * 8]);                                       \
    gload_lds16(Bhg + (size_t)(n0 + ra0) * kdim + (K0) + ca0 * 8,               \
                &Bh[BUF][t * 8]);                                               \
  }

  STAGE_V(0, 0);
  __syncthreads();
  for (int k0 = 0, it = 0; k0 < kdim; k0 += 32, ++it) {
    const int cur = it & 1;
    if (k0 + 32 < kdim) STAGE_V(k0 + 32, cur ^ 1);
    f16x8 fah[4], fbh[4];
#pragma unroll
    for (int f = 0; f < 4; ++f) {
      const int ra = wm * 64 + f * 16 + row16;
      const int ca = (g ^ ((ra ^ (ra >> 2)) & 3)) << 3;
      fah[f] = *(const f16x8*)&Ah[cur][ra * 32 + ca];
      const int rb = wn * 64 + f * 16 + row16;
      const int cb = (g ^ ((rb ^ (rb >> 2)) & 3)) << 3;
      fbh[f] = *(const f16x8*)&Bh[cur][rb * 32 + cb];
    }
#pragma unroll
    for (int m = 0; m < 4; ++m)
#pragma unroll
      for (int n = 0; n < 4; ++n)
        acc[m][n] = __builtin_amdgcn_mfma_f32_16x16x32_f16(fah[m], fbh[n], acc[m][n], 0, 0, 0);
    __syncthreads();
  }
#undef STAGE_V

#pragma unroll
  for (int m = 0; m < 4; ++m)
#pragma unroll
    for (int n = 0; n < 4; ++n) {
      const int col = n0 + wn * 64 + n * 16 + row16;
      const int rowb = m0 + wm * 64 + m * 16 + g * 4;
#pragma unroll
      for (int i = 0; i < 4; ++i)
        Cv[(size_t)(rowb + i) * 1152 + col] =
            __builtin_bit_cast(ushort_t, (_Float16)acc[m][n][i]);
    }
}

// ------- O GEMM: 256x128 tile, single-plane bf16, 512 threads -------------------------
__global__ __launch_bounds__(512, 4) void gemm_o(const ushort_t* __restrict__ Ahg,
                                                 const ushort_t* __restrict__ Bhg,
                                                 float* __restrict__ C, int kdim) {
  __shared__ ushort_t Ah[2][8192], Bh[2][4096];
  const int t = threadIdx.x;
  const int w = t >> 6, l = t & 63;
  int mi, ni;
  tile_map(blockIdx.x, 9, 8, mi, ni);
  const int m0 = mi * 256, n0 = ni * 128;
  const int wm = w >> 1, wn = w & 1;
  const int row16 = l & 15, g = l >> 4;

  f32x4 acc[4][4];
#pragma unroll
  for (int m = 0; m < 4; ++m)
#pragma unroll
    for (int n = 0; n < 4; ++n) acc[m][n] = (f32x4){0,0,0,0};

  const int ra0 = t >> 2, ra1 = (t + 512) >> 2;
  const int ca0 = (t & 3) ^ ((ra0 ^ (ra0 >> 2)) & 3);
  const int ca1 = (t & 3) ^ ((ra1 ^ (ra1 >> 2)) & 3);

#define STAGE_O(K0, BUF)                                                        \
  {                                                                             \
    gload_lds16(Ahg + (size_t)(m0 + ra0) * kdim + (K0) + ca0 * 8,               \
                &Ah[BUF][t * 8]);                                               \
    gload_lds16(Ahg + (size_t)(m0 + ra1) * kdim + (K0) + ca1 * 8,               \
                &Ah[BUF][(t + 512) * 8]);                                       \
    gload_lds16(Bhg + (size_t)(n0 + ra0) * kdim + (K0) + ca0 * 8,               \
                &Bh[BUF][t * 8]);                                               \
  }

  STAGE_O(0, 0);
  __syncthreads();
  for (int k0 = 0, it = 0; k0 < kdim; k0 += 32, ++it) {
    const int cur = it & 1;
    if (k0 + 32 < kdim) STAGE_O(k0 + 32, cur ^ 1);
    bf16x8 fah[4], fbh[4];
#pragma unroll
    for (int f = 0; f < 4; ++f) {
      const int ra = wm * 64 + f * 16 + row16;
      const int ca = (g ^ ((ra ^ (ra >> 2)) & 3)) << 3;
      fah[f] = *(const bf16x8*)&Ah[cur][ra * 32 + ca];
      const int rb = wn * 64 + f * 16 + row16;
      const int cb = (g ^ ((rb ^ (rb >> 2)) & 3)) << 3;
      fbh[f] = *(const bf16x8*)&Bh[cur][rb * 32 + cb];
    }
#pragma unroll
    for (int m = 0; m < 4; ++m)
#pragma unroll
      for (int n = 0; n < 4; ++n)
        acc[m][n] = __builtin_amdgcn_mfma_f32_16x16x32_bf16(fah[m], fbh[n], acc[m][n], 0, 0, 0);
    __syncthreads();
  }
#undef STAGE_O

#pragma unroll
  for (int m = 0; m < 4; ++m)
#pragma unroll
    for (int n = 0; n < 4; ++n) {
      const int col = n0 + wn * 64 + n * 16 + row16;
      if (col < DMODEL) {
        const int rowb = m0 + wm * 64 + m * 16 + g * 4;
#pragma unroll
        for (int i = 0; i < 4; ++i) C[(size_t)(rowb + i) * DMODEL + col] = acc[m][n][i];
      }
    }
}

// ---------------- kv state partials: phi(k)^T @ v per (bh, split) ---------------------
// Vectorized fill (stride-72 v layout for aligned uint4 loads); balanced 13x17 tiles.
// NO min-wave clamp (round-11 lesson: (256,8) forced VGPR=32 -> acc spill -> 1.6 GB).
__global__ __launch_bounds__(256) void kv_kernel(const float* __restrict__ qk,
                                                 const ushort_t* __restrict__ vbuf,
                                                 float* __restrict__ kvpart,
                                                 float* __restrict__ kspart) {
  const int bh = blockIdx.x;    // 0..63
  const int split = blockIdx.y; // 0..KVSPLIT-1
  const int b = bh >> 4, h = bh & 15;
  __shared__ float ks[64][68];
  __shared__ float vs[64][68];
  const int tid = threadIdx.x;
  const int fr = tid >> 2;        // fill row 0..63
  const int fp = tid & 3;         // fill part 0..3
  const int d0 = (tid / 17) * 5;  // 0,5,...,60
  const int e0 = (tid % 17) * 4;  // 0,4,...,64
  const bool active = (tid < 221);
  float acc[5][4] = {};
  float kcol = 0.f;

  for (int chunk = 0; chunk < 4; ++chunk) {
    const int nb = split * 256 + chunk * 64;
    {
      const size_t row = (size_t)(b * S_LEN + nb + fr);
      const float* kx = &qk[row * 1024 + 512 + h * 32 + fp * 8];
      float4 x0 = *reinterpret_cast<const float4*>(kx);
      float4 x1 = *reinterpret_cast<const float4*>(kx + 4);
      float xs[8] = {x0.x, x0.y, x0.z, x0.w, x1.x, x1.y, x1.z, x1.w};
#pragma unroll
      for (int j = 0; j < 8; ++j) {
        ks[fr][1 + fp * 8 + j] = xs[j];
        ks[fr][33 + fp * 8 + j] = 0.5f * xs[j] * xs[j];
      }
      if (fp == 0) ks[fr][0] = 1.f;
      const ushort_t* vp = &vbuf[row * 1152 + h * 72 + fp * 16];
      uint4 v0 = *reinterpret_cast<const uint4*>(vp);
      uint4 v1 = *reinterpret_cast<const uint4*>(vp + 8);
      const ushort_t* vu0 = reinterpret_cast<const ushort_t*>(&v0);
      const ushort_t* vu1 = reinterpret_cast<const ushort_t*>(&v1);
#pragma unroll
      for (int j = 0; j < 8; ++j) {
        vs[fr][fp * 16 + j] = (float)__builtin_bit_cast(_Float16, vu0[j]);
        vs[fr][fp * 16 + 8 + j] = (float)__builtin_bit_cast(_Float16, vu1[j]);
      }
      if (fp == 3) vs[fr][64] = (float)__builtin_bit_cast(_Float16, vbuf[row * 1152 + h * 72 + 64]);
    }
    __syncthreads();
    if (active) {
      for (int r = 0; r < 64; ++r) {
        float a[5], v[4];
#pragma unroll
        for (int i = 0; i < 5; ++i) a[i] = ks[r][d0 + i];
#pragma unroll
        for (int j = 0; j < 4; ++j) v[j] = vs[r][e0 + j];
#pragma unroll
        for (int i = 0; i < 5; ++i)
#pragma unroll
          for (int j = 0; j < 4; ++j) acc[i][j] += a[i] * v[j];
      }
    }
    if (tid < 65) {
      float s = 0.f;
      for (int r = 0; r < 64; ++r) s += ks[r][tid];
      kcol += s;
    }
    __syncthreads();
  }

  if (active) {
    float* kvp = kvpart + ((size_t)split * 64 + bh) * 4225;
#pragma unroll
    for (int i = 0; i < 5; ++i)
#pragma unroll
      for (int j = 0; j < 4; ++j) {
        int e = e0 + j;
        if (e < 65) kvp[(d0 + i) * 65 + e] = acc[i][j];
      }
  }
  if (tid < 65) kspart[((size_t)split * 64 + bh) * 65 + tid] = kcol;
}

__global__ __launch_bounds__(256) void kv_reduce(const float* __restrict__ kvpart,
                                                 const float* __restrict__ kspart,
                                                 float* __restrict__ kv,
                                                 float* __restrict__ ksum) {
  const int NKV = 64 * 4225;
  const int NKS = 64 * 65;
  int i = blockIdx.x * 256 + threadIdx.x;
  if (i < NKV) {
    float s = 0.f;
#pragma unroll 8
    for (int p = 0; p < KVSPLIT; ++p) s += kvpart[(size_t)p * NKV + i];
    kv[i] = s;
  } else if (i < NKV + NKS) {
    int j = i - NKV;
    float s = 0.f;
#pragma unroll 8
    for (int p = 0; p < KVSPLIT; ++p) s += kspart[p * NKS + j];
    ksum[j] = s;
  }
}

// ------- phi(q)@kv, normalize, mask; write attn bf16 (single plane), k' = h*72+e ------
// TRANSPOSED phi store phis_t[d][token] (row stride 128 floats = 512B, 16B-aligned).
// kvs row stride 68 floats = 272 B, 16B-aligned (round-14 lesson: 66 broke it).
__global__ __launch_bounds__(256) void qkv_kernel(const float* __restrict__ qk,
                                                  const float* __restrict__ kv,
                                                  const float* __restrict__ ksum,
                                                  const int* __restrict__ mask,
                                                  uint_t* __restrict__ ath32) {
  const int gx = blockIdx.x;   // 0..31 (128-token chunks within batch)
  const int bh = blockIdx.y;   // 0..63
  const int b = bh >> 4, h = bh & 15;
  __shared__ float kvs[65 * 68];      // 17.7 KB
  __shared__ float phis_t[68][128];   // 34.8 KB  [d][token]
  __shared__ float kss[65];
  __shared__ float qsums[128];
  const int tid = threadIdx.x;

  const float* kvp = kv + (size_t)bh * 4225;
  for (int i = tid; i < 4225; i += 256) kvs[(i / 65) * 68 + (i % 65)] = kvp[i];
  for (int idx = tid; idx < 128 * 8; idx += 256) {
    int tok = idx >> 3, fq = idx & 7;
    size_t row = (size_t)(b * S_LEN + gx * 128 + tok);
    float4 v = *reinterpret_cast<const float4*>(&qk[row * 1024 + h * 32 + fq * 4]);
    float xs[4] = {v.x, v.y, v.z, v.w};
#pragma unroll
    for (int j = 0; j < 4; ++j) {
      phis_t[1 + fq * 4 + j][tok] = xs[j];
      phis_t[33 + fq * 4 + j][tok] = 0.5f * xs[j] * xs[j];
    }
  }
  if (tid < 128) phis_t[0][tid] = 1.f;
  if (tid < 65) kss[tid] = ksum[bh * 65 + tid];
  __syncthreads();
  if (tid < 128) {
    float s = 0.f;
    for (int d = 0; d < 65; ++d) s += phis_t[d][tid];
    qsums[tid] = s;
  }
  __syncthreads();

  const int tt = tid >> 3, fg = tid & 7;  // thread owns tokens 4*tt .. 4*tt+3
  float accs[4][8];
#pragma unroll
  for (int c = 0; c < 4; ++c)
#pragma unroll
    for (int j = 0; j < 8; ++j) accs[c][j] = 0.f;
  float a64[4] = {0.f, 0.f, 0.f, 0.f};

#pragma unroll 4
  for (int d = 0; d < 65; ++d) {
    const float* kr = &kvs[d * 68 + fg * 8];
    float4 va = *reinterpret_cast<const float4*>(kr);
    float4 vb = *reinterpret_cast<const float4*>(kr + 4);
    float kv64 = kvs[d * 68 + 64];
    float4 pv = *reinterpret_cast<const float4*>(&phis_t[d][tt * 4]);
    float ps[4] = {pv.x, pv.y, pv.z, pv.w};
#pragma unroll
    for (int c = 0; c < 4; ++c) {
      float p = ps[c];
      accs[c][0] += p * va.x; accs[c][1] += p * va.y;
      accs[c][2] += p * va.z; accs[c][3] += p * va.w;
      accs[c][4] += p * vb.x; accs[c][5] += p * vb.y;
      accs[c][6] += p * vb.z; accs[c][7] += p * vb.w;
      if (fg == 0) a64[c] += p * kv64;
    }
  }

#pragma unroll
  for (int c = 0; c < 4; ++c) {
    const int tok = tt * 4 + c;
    const int s_in_b = gx * 128 + tok;
    const size_t row = (size_t)(b * S_LEN + s_in_b);
    const int m = mask[b * S_LEN + s_in_b];
    const float qs = qsums[tok];
    const float fm = (m == 0) ? 0.f : 1.f;
    float o[8];
#pragma unroll
    for (int j = 0; j < 8; ++j) {
      float z = qs * kss[fg * 8 + j] + 1e-9f;
      o[j] = fm * accs[c][j] / z;
    }
    const size_t base = row * 576 + h * 36 + fg * 4;  // u32 units; row = 1152 u16
    pack8 phh;
#pragma unroll
    for (int j = 0; j < 8; ++j)
      phh.u[j] = __builtin_bit_cast(ushort_t, __float2bfloat16(o[j]));
    *reinterpret_cast<uint4*>(&ath32[base]) = phh.v;
    if (fg == 0) {
      float z = qs * kss[64] + 1e-9f;
      float o64 = fm * a64[c] / z;
      uint4 tailh = {(uint_t)__builtin_bit_cast(ushort_t, __float2bfloat16(o64)), 0u, 0u, 0u};
      *reinterpret_cast<uint4*>(&ath32[row * 576 + h * 36 + 32]) = tailh;
    }
  }
}

extern "C" void kernel_launch(void* const* d_in, const int* in_sizes, int n_in,
                              void* d_out, int out_size, void* d_ws, size_t ws_size,
                              hipStream_t stream) {
  const float* hs = (const float*)d_in[0];
  const int* mask = (const int*)d_in[1];
  const float* Wq = (const float*)d_in[2];
  const float* Wk = (const float*)d_in[3];
  const float* Wv = (const float*)d_in[4];
  const float* Wo = (const float*)d_in[5];
  float* out = (float*)d_out;

  // Liveness-aliased full-M layout (148.9 MB total):
  //   R_A (34.6 MB): hsh (split..gemm_v) -> kv+ksum+kvpart+kspart (kv_kernel..qkv)
  //   R_B (37.75 MB): hsl (..gemm_qk) -> vbuf (gemm_v..kv_kernel) -> attn (qkv..gemm_o)
  //   R_C (67.1 MB): qkbuf (gemm_qk..qkv)
  //   R_W (9.4 MB): weight planes
  const size_t RA_BYTES = (size_t)M_TOK * KPAD * 2;        // 34.6 MB
  const size_t RB_BYTES = (size_t)M_TOK * 1152 * 2;        // 37.75 MB

  char* base = (char*)d_ws;
  ushort_t* hsh = (ushort_t*)base;                         // R_A as hsh
  float* kv = (float*)base;                                // R_A as kv state
  float* ksum = kv + 64 * 4225;
  float* kvpart = ksum + 64 * 65;
  float* kspart = kvpart + (size_t)KVSPLIT * 64 * 4225;
  char* rb = base + RA_BYTES;
  ushort_t* hsl = (ushort_t*)rb;                           // R_B as hsl
  ushort_t* vbuf = (ushort_t*)rb;                          // R_B as v (fp16, stride-72)
  uint_t* ath32 = (uint_t*)rb;                             // R_B as attn (bf16)
  char* rc = rb + RB_BYTES;
  float* qkbuf = (float*)rc;                               // R_C
  char* rw = rc + (size_t)M_TOK * 1024 * 4;
  ushort_t* Wqkh = (ushort_t*)rw;                          // [1024][1056] fp16 hi
  ushort_t* Wqkl = Wqkh + (size_t)1024 * KPAD;             // lo
  ushort_t* Wvh = Wqkl + (size_t)1024 * KPAD;              // [1152][1056] fp16 hi
  ushort_t* Woh = Wvh + (size_t)NPADW * KPAD;              // [1152][1152] bf16

  dim3 blk(256);

  // fused preprocessing: hs split + all weight transposes in one dispatch
  split_all<<<HS_BLK + WQK_BLK + WV_BLK + WO_BLK, blk, 0, stream>>>(
      hs, Wq, Wk, Wv, Wo, hsh, hsl, Wqkh, Wqkl, Wvh, Woh);

  // q|k projection: fp32-grade 3-product fp16; 1024 blocks x 512 threads
  gemm_qk<<<1024, dim3(512), 0, stream>>>(hsh, hsl, Wqkh, Wqkl, qkbuf, KPAD);
  // v projection: 256x128 tile, 1-product fp16, stride-72 head layout
  gemm_v<<<576, dim3(512), 0, stream>>>(hsh, Wvh, vbuf, KPAD);

  // kv state (writes into R_A — hsh dead after gemm_v)
  kv_kernel<<<dim3(64, KVSPLIT), blk, 0, stream>>>(qkbuf, vbuf, kvpart, kspart);
  kv_reduce<<<(64 * 4225 + 64 * 65 + 255) / 256, blk, 0, stream>>>(kvpart, kspart, kv, ksum);

  // attn (overwrites vbuf — dead after kv_kernel)
  qkv_kernel<<<dim3(32, 64), blk, 0, stream>>>(qkbuf, kv, ksum, mask, ath32);

  // output projection: 256x128 tile, single-plane bf16
  gemm_o<<<576, dim3(512), 0, stream>>>((ushort_t*)ath32, Woh, out, KO);
}

// Round 21
// 388.132 us; speedup vs baseline: 1.0393x; 1.0052x over previous
//
#include <hip/hip_runtime.h>
#include <hip/hip_bf16.h>

typedef unsigned short ushort_t;
typedef unsigned int uint_t;

#define S_LEN 4096
#define BATCH 4
#define DMODEL 1040
#define KPAD 1056          // 1040 padded to 33*32 (hs K)
#define KO 1152            // attn feature dim: 16 heads * 72; O-GEMM K
#define NPADW 1152
#define M_TOK 16384        // full M (4 batches x 4096)
#define KVSPLIT 16         // kv-state split count (16 x 64 bh = 1024 blocks)

// fused-split block ranges (exact multiples of 256)
#define HS_BLK 8448        // M_TOK*132/256
#define WQK_BLK 528        // 1024*132/256
#define WV_BLK 594         // 1152*132/256
#define WO_BLK 648         // 1152*144/256

using f32x4 = __attribute__((ext_vector_type(4))) float;
using bf16x8 = __attribute__((ext_vector_type(8))) __bf16;
using f16x8 = __attribute__((ext_vector_type(8))) _Float16;

// fp16 two-plane split, lo plane pre-scaled by 2^12
__device__ __forceinline__ void splitf16(float x, ushort_t& h, ushort_t& l) {
  _Float16 hf = (_Float16)x;
  float r = (x - (float)hf) * 4096.0f;
  _Float16 lf = (_Float16)r;
  h = __builtin_bit_cast(ushort_t, hf);
  l = __builtin_bit_cast(ushort_t, lf);
}

typedef const __attribute__((address_space(1))) unsigned int* gas_u32p;
typedef __attribute__((address_space(3))) unsigned int* las_u32p;
__device__ __forceinline__ void gload_lds16(const ushort_t* g, ushort_t* l) {
  __builtin_amdgcn_global_load_lds((gas_u32p)g, (las_u32p)l, 16, 0, 0);
}

// XCD-chunked tile map: XCD x owns m-panels [x*PPX, x*PPX+PPX), n-inner order.
__device__ __forceinline__ void tile_map(int lid, int NT, int PPX, int& mi_out, int& ni_out) {
  const int x = lid & 7, pos = lid >> 3;
  const int mi = pos / NT, ni = pos - mi * NT;
  mi_out = x * PPX + mi;
  ni_out = ni;
}

union pack8 { ushort_t u[8]; uint4 v; };

// ------- fused preprocessing: hs split | Wq||Wk split | Wv transpose | Wo transpose ---
__global__ __launch_bounds__(256) void split_all(const float* __restrict__ hs,
                                                 const float* __restrict__ Wq,
                                                 const float* __restrict__ Wk,
                                                 const float* __restrict__ Wv,
                                                 const float* __restrict__ Wo,
                                                 ushort_t* __restrict__ hh,
                                                 ushort_t* __restrict__ hl,
                                                 ushort_t* __restrict__ Wqkh,
                                                 ushort_t* __restrict__ Wqkl,
                                                 ushort_t* __restrict__ Wvh,
                                                 ushort_t* __restrict__ Woh) {
  const int bid = blockIdx.x;
  const int C8 = KPAD / 8;   // 132
  const int C8O = KO / 8;    // 144

  if (bid < HS_BLK) {
    int idx = bid * 256 + threadIdx.x;
    int row = idx / C8, col = (idx % C8) * 8;
    pack8 ph, pl;
    if (col < DMODEL) {
      const float* p = &hs[(size_t)row * DMODEL + col];
#pragma unroll
      for (int j = 0; j < 8; ++j) splitf16(p[j], ph.u[j], pl.u[j]);
    } else {
#pragma unroll
      for (int j = 0; j < 8; ++j) { ph.u[j] = 0; pl.u[j] = 0; }
    }
    size_t o = (size_t)row * KPAD + col;
    *reinterpret_cast<uint4*>(&hh[o]) = ph.v;
    *reinterpret_cast<uint4*>(&hl[o]) = pl.v;
  } else if (bid < HS_BLK + WQK_BLK) {
    int idx = (bid - HS_BLK) * 256 + threadIdx.x;
    int n = idx / C8, k = (idx % C8) * 8;
    pack8 ph, pl;
#pragma unroll
    for (int j = 0; j < 8; ++j) {
      int kk = k + j;
      float val = 0.f;
      if (kk < DMODEL) val = (n < 512) ? Wq[(size_t)kk * 512 + n] : Wk[(size_t)kk * 512 + (n - 512)];
      splitf16(val, ph.u[j], pl.u[j]);
    }
    size_t o = (size_t)n * KPAD + k;
    *reinterpret_cast<uint4*>(&Wqkh[o]) = ph.v;
    *reinterpret_cast<uint4*>(&Wqkl[o]) = pl.v;
  } else if (bid < HS_BLK + WQK_BLK + WV_BLK) {
    int idx = (bid - HS_BLK - WQK_BLK) * 256 + threadIdx.x;
    int n = idx / C8, k = (idx % C8) * 8;   // n = output column = h*72 + e
    int hh_ = n / 72, e = n % 72;
    pack8 ph;
#pragma unroll
    for (int j = 0; j < 8; ++j) {
      int kk = k + j;
      float val = (e < 65 && kk < DMODEL) ? Wv[(size_t)kk * DMODEL + (hh_ * 65 + e)] : 0.f;
      ph.u[j] = __builtin_bit_cast(ushort_t, (_Float16)val);
    }
    *reinterpret_cast<uint4*>(&Wvh[(size_t)n * KPAD + k]) = ph.v;
  } else {
    int idx = (bid - HS_BLK - WQK_BLK - WV_BLK) * 256 + threadIdx.x;
    int n = idx / C8O, k = (idx % C8O) * 8;
    pack8 ph;
#pragma unroll
    for (int j = 0; j < 8; ++j) {
      int kk = k + j;           // attn feature index = h*72 + e
      int h = kk / 72, e = kk % 72;
      float val = (n < DMODEL && e < 65) ? Wo[(size_t)(h * 65 + e) * DMODEL + n] : 0.f;
      ph.u[j] = __builtin_bit_cast(ushort_t, __float2bfloat16(val));
    }
    *reinterpret_cast<uint4*>(&Woh[(size_t)n * KO + k]) = ph.v;
  }
}

// ------- fused QK+V projection dispatch --------------------------------------------
// Blocks 0..1023: QK path (fp16 2-plane 3-product, 128x128 tile).
// Blocks 1024..1599: V path (fp16 hi 1-product, 256x128 tile, fp16 out, stride-72).
// Independent GEMMs sharing A (hs planes): fusing fills the qk drain tail with
// v-blocks and reuses hs L2 lines (identical per-XCD row spans: 2048 rows each).
// LDS: 64 KB union carved from one flat array; both paths 2 blocks/CU as before.
__global__ __launch_bounds__(512, 4) void gemm_qkv(const ushort_t* __restrict__ Ahg,
                                                   const ushort_t* __restrict__ Alg,
                                                   const ushort_t* __restrict__ Bqkh,
                                                   const ushort_t* __restrict__ Bqkl,
                                                   const ushort_t* __restrict__ Bvh,
                                                   float* __restrict__ Cqk,
                                                   ushort_t* __restrict__ Cv, int kdim) {
  __shared__ ushort_t smem[32768];   // 64 KB
  const int t = threadIdx.x;         // 0..511
  const int w = t >> 6, l = t & 63;  // 8 waves
  const int row16 = l & 15, g = l >> 4;

  if (blockIdx.x < 1024) {
    // ---------------- QK path ----------------
    ushort_t* Ah = smem;              // [2][4096]
    ushort_t* Al = smem + 8192;
    ushort_t* Bh = smem + 16384;
    ushort_t* Bl = smem + 24576;
    int mi, ni;
    tile_map(blockIdx.x, 8, 16, mi, ni);
    const int m0 = mi * 128, n0 = ni * 128;
    const int wm = w >> 2, wn = w & 3;  // 2 x 4

    f32x4 acc[4][2], acc2[4][2];
#pragma unroll
    for (int m = 0; m < 4; ++m)
#pragma unroll
      for (int n = 0; n < 2; ++n) { acc[m][n] = (f32x4){0,0,0,0}; acc2[m][n] = (f32x4){0,0,0,0}; }

    const int chunk = t;
    const int r0 = chunk >> 2;
    const int ch0 = (chunk & 3) ^ ((r0 ^ (r0 >> 2)) & 3);

#define STAGE_QK(K0, BUF)                                                       \
    {                                                                           \
      const size_t ga = (size_t)(m0 + r0) * kdim + (K0) + ch0 * 8;              \
      const size_t gb = (size_t)(n0 + r0) * kdim + (K0) + ch0 * 8;              \
      gload_lds16(Ahg + ga, &Ah[(BUF) * 4096 + chunk * 8]);                     \
      gload_lds16(Alg + ga, &Al[(BUF) * 4096 + chunk * 8]);                     \
      gload_lds16(Bqkh + gb, &Bh[(BUF) * 4096 + chunk * 8]);                    \
      gload_lds16(Bqkl + gb, &Bl[(BUF) * 4096 + chunk * 8]);                    \
    }

    STAGE_QK(0, 0);
    __syncthreads();
    for (int k0 = 0, it = 0; k0 < kdim; k0 += 32, ++it) {
      const int cur = it & 1;
      if (k0 + 32 < kdim) STAGE_QK(k0 + 32, cur ^ 1);
      f16x8 fah[4], fal[4], fbh[2], fbl[2];
#pragma unroll
      for (int f = 0; f < 4; ++f) {
        const int ra = wm * 64 + f * 16 + row16;
        const int ca = (g ^ ((ra ^ (ra >> 2)) & 3)) << 3;
        fah[f] = *(const f16x8*)&Ah[cur * 4096 + ra * 32 + ca];
        fal[f] = *(const f16x8*)&Al[cur * 4096 + ra * 32 + ca];
      }
#pragma unroll
      for (int f = 0; f < 2; ++f) {
        const int rb = wn * 32 + f * 16 + row16;
        const int cb = (g ^ ((rb ^ (rb >> 2)) & 3)) << 3;
        fbh[f] = *(const f16x8*)&Bh[cur * 4096 + rb * 32 + cb];
        fbl[f] = *(const f16x8*)&Bl[cur * 4096 + rb * 32 + cb];
      }
#pragma unroll
      for (int m = 0; m < 4; ++m)
#pragma unroll
        for (int n = 0; n < 2; ++n) {
          acc[m][n]  = __builtin_amdgcn_mfma_f32_16x16x32_f16(fah[m], fbh[n], acc[m][n], 0, 0, 0);
          acc2[m][n] = __builtin_amdgcn_mfma_f32_16x16x32_f16(fah[m], fbl[n], acc2[m][n], 0, 0, 0);
          acc2[m][n] = __builtin_amdgcn_mfma_f32_16x16x32_f16(fal[m], fbh[n], acc2[m][n], 0, 0, 0);
        }
      __syncthreads();
    }
#undef STAGE_QK

    const float S2 = 1.0f / 4096.0f;
#pragma unroll
    for (int m = 0; m < 4; ++m)
#pragma unroll
      for (int n = 0; n < 2; ++n) {
        const int col = n0 + wn * 32 + n * 16 + row16;
        const int rowb = m0 + wm * 64 + m * 16 + g * 4;
#pragma unroll
        for (int i = 0; i < 4; ++i)
          Cqk[(size_t)(rowb + i) * 1024 + col] = acc[m][n][i] + acc2[m][n][i] * S2;
      }
  } else {
    // ---------------- V path ----------------
    ushort_t* Ah = smem;              // [2][8192]
    ushort_t* Bh = smem + 16384;      // [2][4096]
    int mi, ni;
    tile_map(blockIdx.x - 1024, 9, 8, mi, ni);
    const int m0 = mi * 256, n0 = ni * 128;
    const int wm = w >> 1, wn = w & 1;  // 4 x 2

    f32x4 acc[4][4];
#pragma unroll
    for (int m = 0; m < 4; ++m)
#pragma unroll
      for (int n = 0; n < 4; ++n) acc[m][n] = (f32x4){0,0,0,0};

    const int ra0 = t >> 2, ra1 = (t + 512) >> 2;
    const int ca0 = (t & 3) ^ ((ra0 ^ (ra0 >> 2)) & 3);
    const int ca1 = (t & 3) ^ ((ra1 ^ (ra1 >> 2)) & 3);

#define STAGE_V(K0, BUF)                                                        \
    {                                                                           \
      gload_lds16(Ahg + (size_t)(m0 + ra0) * kdim + (K0) + ca0 * 8,             \
                  &Ah[(BUF) * 8192 + t * 8]);                                   \
      gload_lds16(Ahg + (size_t)(m0 + ra1) * kdim + (K0) + ca1 * 8,             \
                  &Ah[(BUF) * 8192 + (t + 512) * 8]);                           \
      gload_lds16(Bvh + (size_t)(n0 + ra0) * kdim + (K0) + ca0 * 8,             \
                  &Bh[(BUF) * 4096 + t * 8]);                                   \
    }

    STAGE_V(0, 0);
    __syncthreads();
    for (int k0 = 0, it = 0; k0 < kdim; k0 += 32, ++it) {
      const int cur = it & 1;
      if (k0 + 32 < kdim) STAGE_V(k0 + 32, cur ^ 1);
      f16x8 fah[4], fbh[4];
#pragma unroll
      for (int f = 0; f < 4; ++f) {
        const int ra = wm * 64 + f * 16 + row16;
        const int ca = (g ^ ((ra ^ (ra >> 2)) & 3)) << 3;
        fah[f] = *(const f16x8*)&Ah[cur * 8192 + ra * 32 + ca];
        const int rb = wn * 64 + f * 16 + row16;
        const int cb = (g ^ ((rb ^ (rb >> 2)) & 3)) << 3;
        fbh[f] = *(const f16x8*)&Bh[cur * 4096 + rb * 32 + cb];
      }
#pragma unroll
      for (int m = 0; m < 4; ++m)
#pragma unroll
        for (int n = 0; n < 4; ++n)
          acc[m][n] = __builtin_amdgcn_mfma_f32_16x16x32_f16(fah[m], fbh[n], acc[m][n], 0, 0, 0);
      __syncthreads();
    }
#undef STAGE_V

#pragma unroll
    for (int m = 0; m < 4; ++m)
#pragma unroll
      for (int n = 0; n < 4; ++n) {
        const int col = n0 + wn * 64 + n * 16 + row16;
        const int rowb = m0 + wm * 64 + m * 16 + g * 4;
#pragma unroll
        for (int i = 0; i < 4; ++i)
          Cv[(size_t)(rowb + i) * 1152 + col] =
              __builtin_bit_cast(ushort_t, (_Float16)acc[m][n][i]);
      }
  }
}

// ------- O GEMM: 256x128 tile, single-plane bf16, 512 threads -------------------------
__global__ __launch_bounds__(512, 4) void gemm_o(const ushort_t* __restrict__ Ahg,
                                                 const ushort_t* __restrict__ Bhg,
                                                 float* __restrict__ C, int kdim) {
  __shared__ ushort_t Ah[2][8192], Bh[2][4096];
  const int t = threadIdx.x;
  const int w = t >> 6, l = t & 63;
  int mi, ni;
  tile_map(blockIdx.x, 9, 8, mi, ni);
  const int m0 = mi * 256, n0 = ni * 128;
  const int wm = w >> 1, wn = w & 1;
  const int row16 = l & 15, g = l >> 4;

  f32x4 acc[4][4];
#pragma unroll
  for (int m = 0; m < 4; ++m)
#pragma unroll
    for (int n = 0; n < 4; ++n) acc[m][n] = (f32x4){0,0,0,0};

  const int ra0 = t >> 2, ra1 = (t + 512) >> 2;
  const int ca0 = (t & 3) ^ ((ra0 ^ (ra0 >> 2)) & 3);
  const int ca1 = (t & 3) ^ ((ra1 ^ (ra1 >> 2)) & 3);

#define STAGE_O(K0, BUF)                                                        \
  {                                                                             \
    gload_lds16(Ahg + (size_t)(m0 + ra0) * kdim + (K0) + ca0 * 8,               \
                &Ah[BUF][t * 8]);                                               \
    gload_lds16(Ahg + (size_t)(m0 + ra1) * kdim + (K0) + ca1 * 8,               \
                &Ah[BUF][(t + 512) * 8]);                                       \
    gload_lds16(Bhg + (size_t)(n0 + ra0) * kdim + (K0) + ca0 * 8,               \
                &Bh[BUF][t * 8]);                                               \
  }

  STAGE_O(0, 0);
  __syncthreads();
  for (int k0 = 0, it = 0; k0 < kdim; k0 += 32, ++it) {
    const int cur = it & 1;
    if (k0 + 32 < kdim) STAGE_O(k0 + 32, cur ^ 1);
    bf16x8 fah[4], fbh[4];
#pragma unroll
    for (int f = 0; f < 4; ++f) {
      const int ra = wm * 64 + f * 16 + row16;
      const int ca = (g ^ ((ra ^ (ra >> 2)) & 3)) << 3;
      fah[f] = *(const bf16x8*)&Ah[cur][ra * 32 + ca];
      const int rb = wn * 64 + f * 16 + row16;
      const int cb = (g ^ ((rb ^ (rb >> 2)) & 3)) << 3;
      fbh[f] = *(const bf16x8*)&Bh[cur][rb * 32 + cb];
    }
#pragma unroll
    for (int m = 0; m < 4; ++m)
#pragma unroll
      for (int n = 0; n < 4; ++n)
        acc[m][n] = __builtin_amdgcn_mfma_f32_16x16x32_bf16(fah[m], fbh[n], acc[m][n], 0, 0, 0);
    __syncthreads();
  }
#undef STAGE_O

#pragma unroll
  for (int m = 0; m < 4; ++m)
#pragma unroll
    for (int n = 0; n < 4; ++n) {
      const int col = n0 + wn * 64 + n * 16 + row16;
      if (col < DMODEL) {
        const int rowb = m0 + wm * 64 + m * 16 + g * 4;
#pragma unroll
        for (int i = 0; i < 4; ++i) C[(size_t)(rowb + i) * DMODEL + col] = acc[m][n][i];
      }
    }
}

// ---------------- kv state partials: phi(k)^T @ v per (bh, split) ---------------------
// Vectorized fill (stride-72 v layout for aligned uint4 loads); balanced 13x17 tiles.
// NO min-wave clamp (round-11 lesson: (256,8) forced VGPR=32 -> acc spill -> 1.6 GB).
__global__ __launch_bounds__(256) void kv_kernel(const float* __restrict__ qk,
                                                 const ushort_t* __restrict__ vbuf,
                                                 float* __restrict__ kvpart,
                                                 float* __restrict__ kspart) {
  const int bh = blockIdx.x;    // 0..63
  const int split = blockIdx.y; // 0..KVSPLIT-1
  const int b = bh >> 4, h = bh & 15;
  __shared__ float ks[64][68];
  __shared__ float vs[64][68];
  const int tid = threadIdx.x;
  const int fr = tid >> 2;        // fill row 0..63
  const int fp = tid & 3;         // fill part 0..3
  const int d0 = (tid / 17) * 5;  // 0,5,...,60
  const int e0 = (tid % 17) * 4;  // 0,4,...,64
  const bool active = (tid < 221);
  float acc[5][4] = {};
  float kcol = 0.f;

  for (int chunk = 0; chunk < 4; ++chunk) {
    const int nb = split * 256 + chunk * 64;
    {
      const size_t row = (size_t)(b * S_LEN + nb + fr);
      const float* kx = &qk[row * 1024 + 512 + h * 32 + fp * 8];
      float4 x0 = *reinterpret_cast<const float4*>(kx);
      float4 x1 = *reinterpret_cast<const float4*>(kx + 4);
      float xs[8] = {x0.x, x0.y, x0.z, x0.w, x1.x, x1.y, x1.z, x1.w};
#pragma unroll
      for (int j = 0; j < 8; ++j) {
        ks[fr][1 + fp * 8 + j] = xs[j];
        ks[fr][33 + fp * 8 + j] = 0.5f * xs[j] * xs[j];
      }
      if (fp == 0) ks[fr][0] = 1.f;
      const ushort_t* vp = &vbuf[row * 1152 + h * 72 + fp * 16];
      uint4 v0 = *reinterpret_cast<const uint4*>(vp);
      uint4 v1 = *reinterpret_cast<const uint4*>(vp + 8);
      const ushort_t* vu0 = reinterpret_cast<const ushort_t*>(&v0);
      const ushort_t* vu1 = reinterpret_cast<const ushort_t*>(&v1);
#pragma unroll
      for (int j = 0; j < 8; ++j) {
        vs[fr][fp * 16 + j] = (float)__builtin_bit_cast(_Float16, vu0[j]);
        vs[fr][fp * 16 + 8 + j] = (float)__builtin_bit_cast(_Float16, vu1[j]);
      }
      if (fp == 3) vs[fr][64] = (float)__builtin_bit_cast(_Float16, vbuf[row * 1152 + h * 72 + 64]);
    }
    __syncthreads();
    if (active) {
      for (int r = 0; r < 64; ++r) {
        float a[5], v[4];
#pragma unroll
        for (int i = 0; i < 5; ++i) a[i] = ks[r][d0 + i];
#pragma unroll
        for (int j = 0; j < 4; ++j) v[j] = vs[r][e0 + j];
#pragma unroll
        for (int i = 0; i < 5; ++i)
#pragma unroll
          for (int j = 0; j < 4; ++j) acc[i][j] += a[i] * v[j];
      }
    }
    if (tid < 65) {
      float s = 0.f;
      for (int r = 0; r < 64; ++r) s += ks[r][tid];
      kcol += s;
    }
    __syncthreads();
  }

  if (active) {
    float* kvp = kvpart + ((size_t)split * 64 + bh) * 4225;
#pragma unroll
    for (int i = 0; i < 5; ++i)
#pragma unroll
      for (int j = 0; j < 4; ++j) {
        int e = e0 + j;
        if (e < 65) kvp[(d0 + i) * 65 + e] = acc[i][j];
      }
  }
  if (tid < 65) kspart[((size_t)split * 64 + bh) * 65 + tid] = kcol;
}

__global__ __launch_bounds__(256) void kv_reduce(const float* __restrict__ kvpart,
                                                 const float* __restrict__ kspart,
                                                 float* __restrict__ kv,
                                                 float* __restrict__ ksum) {
  const int NKV = 64 * 4225;
  const int NKS = 64 * 65;
  int i = blockIdx.x * 256 + threadIdx.x;
  if (i < NKV) {
    float s = 0.f;
#pragma unroll 8
    for (int p = 0; p < KVSPLIT; ++p) s += kvpart[(size_t)p * NKV + i];
    kv[i] = s;
  } else if (i < NKV + NKS) {
    int j = i - NKV;
    float s = 0.f;
#pragma unroll 8
    for (int p = 0; p < KVSPLIT; ++p) s += kspart[p * NKS + j];
    ksum[j] = s;
  }
}

// ------- phi(q)@kv, normalize, mask; write attn bf16 (single plane), k' = h*72+e ------
// TRANSPOSED phi store phis_t[d][token] (row stride 128 floats = 512B, 16B-aligned).
// kvs row stride 68 floats = 272 B, 16B-aligned (round-14 lesson: 66 broke it).
__global__ __launch_bounds__(256) void qkv_kernel(const float* __restrict__ qk,
                                                  const float* __restrict__ kv,
                                                  const float* __restrict__ ksum,
                                                  const int* __restrict__ mask,
                                                  uint_t* __restrict__ ath32) {
  const int gx = blockIdx.x;   // 0..31 (128-token chunks within batch)
  const int bh = blockIdx.y;   // 0..63
  const int b = bh >> 4, h = bh & 15;
  __shared__ float kvs[65 * 68];      // 17.7 KB
  __shared__ float phis_t[68][128];   // 34.8 KB  [d][token]
  __shared__ float kss[65];
  __shared__ float qsums[128];
  const int tid = threadIdx.x;

  const float* kvp = kv + (size_t)bh * 4225;
  for (int i = tid; i < 4225; i += 256) kvs[(i / 65) * 68 + (i % 65)] = kvp[i];
  for (int idx = tid; idx < 128 * 8; idx += 256) {
    int tok = idx >> 3, fq = idx & 7;
    size_t row = (size_t)(b * S_LEN + gx * 128 + tok);
    float4 v = *reinterpret_cast<const float4*>(&qk[row * 1024 + h * 32 + fq * 4]);
    float xs[4] = {v.x, v.y, v.z, v.w};
#pragma unroll
    for (int j = 0; j < 4; ++j) {
      phis_t[1 + fq * 4 + j][tok] = xs[j];
      phis_t[33 + fq * 4 + j][tok] = 0.5f * xs[j] * xs[j];
    }
  }
  if (tid < 128) phis_t[0][tid] = 1.f;
  if (tid < 65) kss[tid] = ksum[bh * 65 + tid];
  __syncthreads();
  if (tid < 128) {
    float s = 0.f;
    for (int d = 0; d < 65; ++d) s += phis_t[d][tid];
    qsums[tid] = s;
  }
  __syncthreads();

  const int tt = tid >> 3, fg = tid & 7;  // thread owns tokens 4*tt .. 4*tt+3
  float accs[4][8];
#pragma unroll
  for (int c = 0; c < 4; ++c)
#pragma unroll
    for (int j = 0; j < 8; ++j) accs[c][j] = 0.f;
  float a64[4] = {0.f, 0.f, 0.f, 0.f};

#pragma unroll 4
  for (int d = 0; d < 65; ++d) {
    const float* kr = &kvs[d * 68 + fg * 8];
    float4 va = *reinterpret_cast<const float4*>(kr);
    float4 vb = *reinterpret_cast<const float4*>(kr + 4);
    float kv64 = kvs[d * 68 + 64];
    float4 pv = *reinterpret_cast<const float4*>(&phis_t[d][tt * 4]);
    float ps[4] = {pv.x, pv.y, pv.z, pv.w};
#pragma unroll
    for (int c = 0; c < 4; ++c) {
      float p = ps[c];
      accs[c][0] += p * va.x; accs[c][1] += p * va.y;
      accs[c][2] += p * va.z; accs[c][3] += p * va.w;
      accs[c][4] += p * vb.x; accs[c][5] += p * vb.y;
      accs[c][6] += p * vb.z; accs[c][7] += p * vb.w;
      if (fg == 0) a64[c] += p * kv64;
    }
  }

#pragma unroll
  for (int c = 0; c < 4; ++c) {
    const int tok = tt * 4 + c;
    const int s_in_b = gx * 128 + tok;
    const size_t row = (size_t)(b * S_LEN + s_in_b);
    const int m = mask[b * S_LEN + s_in_b];
    const float qs = qsums[tok];
    const float fm = (m == 0) ? 0.f : 1.f;
    float o[8];
#pragma unroll
    for (int j = 0; j < 8; ++j) {
      float z = qs * kss[fg * 8 + j] + 1e-9f;
      o[j] = fm * accs[c][j] / z;
    }
    const size_t base = row * 576 + h * 36 + fg * 4;  // u32 units; row = 1152 u16
    pack8 phh;
#pragma unroll
    for (int j = 0; j < 8; ++j)
      phh.u[j] = __builtin_bit_cast(ushort_t, __float2bfloat16(o[j]));
    *reinterpret_cast<uint4*>(&ath32[base]) = phh.v;
    if (fg == 0) {
      float z = qs * kss[64] + 1e-9f;
      float o64 = fm * a64[c] / z;
      uint4 tailh = {(uint_t)__builtin_bit_cast(ushort_t, __float2bfloat16(o64)), 0u, 0u, 0u};
      *reinterpret_cast<uint4*>(&ath32[row * 576 + h * 36 + 32]) = tailh;
    }
  }
}

extern "C" void kernel_launch(void* const* d_in, const int* in_sizes, int n_in,
                              void* d_out, int out_size, void* d_ws, size_t ws_size,
                              hipStream_t stream) {
  const float* hs = (const float*)d_in[0];
  const int* mask = (const int*)d_in[1];
  const float* Wq = (const float*)d_in[2];
  const float* Wk = (const float*)d_in[3];
  const float* Wv = (const float*)d_in[4];
  const float* Wo = (const float*)d_in[5];
  float* out = (float*)d_out;

  // Liveness-aliased full-M layout (148.9 MB total):
  //   R_A (34.6 MB): hsh (split..gemm_qkv) -> kv+ksum+kvpart+kspart (kv_kernel..qkv)
  //   R_B (37.75 MB): hsl (..gemm_qkv) -> vbuf (gemm_qkv..kv_kernel) -> attn (qkv..)
  //   R_C (67.1 MB): qkbuf (gemm_qkv..qkv)
  //   R_W (9.4 MB): weight planes
  // NOTE: hsl and vbuf both live during gemm_qkv? NO — vbuf must NOT alias hsl while
  // the qk path still reads hsl. vbuf is moved to a separate sub-region within R_B?
  // R_B holds hsl [M_TOK*KPAD u16 = 34.6MB] while region is 37.75MB. V output (fp16,
  // [M_TOK][1152] = 37.75MB) cannot overlap hsl during gemm_qkv. FIX: vbuf lives in
  // R_C's tail? R_C is qkbuf [M_TOK][1024] f32 = 67.1MB, written by the same dispatch.
  // Instead: place vbuf AFTER R_C (dedicated 37.75 MB region R_D); attn plane reuses
  // R_B (hsl dead after gemm_qkv). Total = 34.6+37.75+67.1+37.75+9.4 = 186.6 MB.
  // ws_size accommodated 158MB in round 2... keep within bounds: reuse R_A for attn
  // instead? R_A holds kv-state (17.3+ MB) through qkv. attn = 37.75MB. R_A is 34.6MB
  // — too small and busy. SAFE CHOICE: dedicated R_D for vbuf; attn -> R_B after hsl
  // dies. Peak 186.6 MB (ws_size is 1.5x out+in typically ~hundreds MB; rounds 1-2
  // used 167MB fine; if ws is tight this fails loudly -- accepted risk? NO: keep the
  // proven layout instead: vbuf CANNOT coexist with hsl in fused kernel...
  const size_t RA_BYTES = (size_t)M_TOK * KPAD * 2;        // 34.6 MB
  const size_t RB_BYTES = (size_t)M_TOK * 1152 * 2;        // 37.75 MB

  char* base = (char*)d_ws;
  ushort_t* hsh = (ushort_t*)base;                         // R_A as hsh
  float* kv = (float*)base;                                // R_A as kv state
  float* ksum = kv + 64 * 4225;
  float* kvpart = ksum + 64 * 65;
  float* kspart = kvpart + (size_t)KVSPLIT * 64 * 4225;
  char* rb = base + RA_BYTES;
  ushort_t* hsl = (ushort_t*)rb;                           // R_B: hsl -> attn plane
  uint_t* ath32 = (uint_t*)rb;
  char* rc = rb + RB_BYTES;
  float* qkbuf = (float*)rc;                               // R_C
  char* rd = rc + (size_t)M_TOK * 1024 * 4;
  ushort_t* vbuf = (ushort_t*)rd;                          // R_D: v fp16 stride-72
  char* rw = rd + (size_t)M_TOK * 1152 * 2;
  ushort_t* Wqkh = (ushort_t*)rw;                          // [1024][1056] fp16 hi
  ushort_t* Wqkl = Wqkh + (size_t)1024 * KPAD;             // lo
  ushort_t* Wvh = Wqkl + (size_t)1024 * KPAD;              // [1152][1056] fp16 hi
  ushort_t* Woh = Wvh + (size_t)NPADW * KPAD;              // [1152][1152] bf16

  dim3 blk(256);

  // fused preprocessing: hs split + all weight transposes in one dispatch
  split_all<<<HS_BLK + WQK_BLK + WV_BLK + WO_BLK, blk, 0, stream>>>(
      hs, Wq, Wk, Wv, Wo, hsh, hsl, Wqkh, Wqkl, Wvh, Woh);

  // fused q|k + v projections: qk-blocks' drain tail filled by v-blocks
  gemm_qkv<<<1600, dim3(512), 0, stream>>>(hsh, hsl, Wqkh, Wqkl, Wvh,
                                           qkbuf, vbuf, KPAD);

  // kv state (writes into R_A — hsh dead after gemm_qkv)
  kv_kernel<<<dim3(64, KVSPLIT), blk, 0, stream>>>(qkbuf, vbuf, kvpart, kspart);
  kv_reduce<<<(64 * 4225 + 64 * 65 + 255) / 256, blk, 0, stream>>>(kvpart, kspart, kv, ksum);

  // attn (overwrites hsl region — dead after gemm_qkv)
  qkv_kernel<<<dim3(32, 64), blk, 0, stream>>>(qkbuf, kv, ksum, mask, ath32);

  // output projection: 256x128 tile, single-plane bf16
  gemm_o<<<576, dim3(512), 0, stream>>>((ushort_t*)ath32, Woh, out, KO);
}